// Round 9
// baseline (487.350 us; speedup 1.0000x reference)
//
#include <hip/hip_runtime.h>
#include <stdint.h>

typedef __attribute__((ext_vector_type(8))) short bf16x8;
typedef __attribute__((ext_vector_type(8))) unsigned short u16x8;
typedef __attribute__((ext_vector_type(4))) float f32x4;
typedef __attribute__((ext_vector_type(2))) uint32_t u32x2;

#define DEV __device__ __forceinline__

// ws layout in ushort elements
constexpr size_t WQ_PK    = 0;         // 65536 elems
constexpr size_t WPROJ_PK = 65536;     // 65536 elems
constexpr size_t WP_PK    = 131072;    // 4 * 131072 elems
constexpr size_t KVBUF    = 655360;    // 4096*21*512 = 44040192 elems
// kvbuf layout: [b][row 0..20][o 0..511] bf16, producer-coalesced.

constexpr float SCALE_Q  = 0.17677669529663687f;  // 32^-0.5

DEV uint16_t f2bf(float f){
  uint32_t u = __builtin_bit_cast(uint32_t, f);
  u += 0x7fffu + ((u >> 16) & 1u);
  return (uint16_t)(u >> 16);
}

DEV uint32_t cvtpk(float a, float b){
  uint32_t r;
  asm("v_cvt_pk_bf16_f32 %0, %1, %2" : "=v"(r) : "v"(a), "v"(b));
  return r;
}

// out[j] = (j<4 ? a[2j+par] : b[2(j-4)+par]) via byte-perm selector
DEV u16x8 extract_par(u16x8 a, u16x8 b, uint32_t sel){
  union U { u16x8 v; uint32_t d[4]; } A, B, R;
  A.v = a; B.v = b;
  R.d[0] = __builtin_amdgcn_perm(A.d[1], A.d[0], sel);
  R.d[1] = __builtin_amdgcn_perm(A.d[3], A.d[2], sel);
  R.d[2] = __builtin_amdgcn_perm(B.d[1], B.d[0], sel);
  R.d[3] = __builtin_amdgcn_perm(B.d[3], B.d[2], sel);
  return R.v;
}

// ---------------------------------------------------------------------------
// K0: prepack weights into MFMA fragment layout, f32 -> bf16.
// frag (nt,kt): lane l, j supplies W[n=nt*16+(l&15)][k=kt*32+(l>>4)*8+j].
// ---------------------------------------------------------------------------
__global__ __launch_bounds__(256) void k_prepack(
    const float* __restrict__ wq,  const float* __restrict__ wp1,
    const float* __restrict__ wp2, const float* __restrict__ wp3,
    const float* __restrict__ wp4, const float* __restrict__ wproj,
    uint16_t* __restrict__ ws)
{
  int f = blockIdx.x * 256 + threadIdx.x;   // 0..81919 fragment id
  const float* src; uint16_t* dst; int g;
  if (f < 8192)       { src = wq;    dst = ws + WQ_PK;    g = f; }
  else if (f < 16384) { src = wproj; dst = ws + WPROJ_PK; g = f - 8192; }
  else {
    int j = (f - 16384) >> 14;
    src = j == 0 ? wp1 : j == 1 ? wp2 : j == 2 ? wp3 : wp4;
    dst = ws + WP_PK + (size_t)j * 131072;
    g = (f - 16384) & 16383;
  }
  int l = g & 63, kt = (g >> 6) & 7, nt = g >> 9;
  int n  = nt * 16 + (l & 15);
  int k0 = kt * 32 + (l >> 4) * 8;
  const float* s = src + (size_t)n * 256 + k0;
  u16x8 v;
  #pragma unroll
  for (int j = 0; j < 8; ++j) v[j] = f2bf(s[j]);
  *reinterpret_cast<u16x8*>(dst + (size_t)g * 8) = v;
}

// ---------------------------------------------------------------------------
// K1: depthwise convs + pointwise (swapped MFMA) -> kvbuf2[b][row][o] (bf16).
// 8 batches per block, 512 threads (8 waves). LDS 86016 B.
// dT [168][256] ushort, swizzled: byte = (row*512 + c*2) ^ ((row&7)<<4)
// ---------------------------------------------------------------------------
__global__ __launch_bounds__(512, 2) void k_kv(
    const float* __restrict__ x,
    const float* __restrict__ wd1, const float* __restrict__ bd1, const float* __restrict__ bp1,
    const float* __restrict__ wd2, const float* __restrict__ bd2, const float* __restrict__ bp2,
    const float* __restrict__ wd3, const float* __restrict__ bd3, const float* __restrict__ bp3,
    const float* __restrict__ wd4, const float* __restrict__ bd4, const float* __restrict__ bp4,
    const uint16_t* __restrict__ ws, uint16_t* __restrict__ kvbuf)
{
  extern __shared__ char smem[];  // 86016 B
  const int t = threadIdx.x, lane = t & 63, w = t >> 6;
  const int q4 = lane >> 4, c15 = lane & 15;
  const int b0 = blockIdx.x * 8;

  constexpr int DILA[4] = {1,2,3,4}, PADA[4] = {0,0,1,2}, OWA[4] = {3,2,2,2};
  constexpr int HWA[4]  = {9,4,4,4}, OFFA[4] = {0,9,13,17}, MTA[4] = {5,2,2,2};

  // ---- depthwise conv, all branches; write dT (bf16) to LDS ----
  {
    const int c = t & 255, half = t >> 8;
    for (int pass = 0; pass < 4; ++pass){
      const int bh = pass * 2 + half;
      float xr[49];
      #pragma unroll
      for (int p = 0; p < 49; ++p)
        xr[p] = x[((size_t)(b0 + bh) * 49 + p) * 256 + c];
      #pragma unroll
      for (int j = 0; j < 4; ++j){
        const float* wdp = j==0?wd1:j==1?wd2:j==2?wd3:wd4;
        const float* bdp = j==0?bd1:j==1?bd2:j==2?bd3:bd4;
        float wv[9];
        #pragma unroll
        for (int q = 0; q < 9; ++q) wv[q] = wdp[c * 9 + q];
        const float bdv = bdp[c];
        #pragma unroll
        for (int oy = 0; oy < OWA[j]; ++oy)
        #pragma unroll
        for (int ox = 0; ox < OWA[j]; ++ox){
          float acc = bdv;
          #pragma unroll
          for (int ky = 0; ky < 3; ++ky){
            const int yy = oy * 2 - PADA[j] + ky * DILA[j];
            if (yy < 0 || yy > 6) continue;
            #pragma unroll
            for (int kx = 0; kx < 3; ++kx){
              const int xx = ox * 2 - PADA[j] + kx * DILA[j];
              if (xx < 0 || xx > 6) continue;
              acc += xr[yy * 7 + xx] * wv[ky * 3 + kx];
            }
          }
          const int row = bh * 21 + OFFA[j] + oy * OWA[j] + ox;
          *reinterpret_cast<uint16_t*>(smem + ((row * 512 + c * 2) ^ ((row & 7) << 4))) = f2bf(acc);
        }
      }
    }
  }
  __syncthreads();

  // ---- pointwise GEMM per branch, swapped: D^T[o][m] = Wp * dT^T ----
  #pragma unroll
  for (int j = 0; j < 4; ++j){
    const uint16_t* pk = ws + WP_PK + (size_t)j * 131072;
    const float* bpp = j==0?bp1:j==1?bp2:j==2?bp3:bp4;
    const int hw = HWA[j], off = OFFA[j], MV = hw * 8, ST = MTA[j];
    for (int st = 0; st < ST; ++st){
      const int sl = st * 16 + c15;
      const bool sv = sl < MV;
      const int svc = sv ? sl : 0;
      const int bh = svc / hw, sp = svc - bh * hw;
      const int arow = bh * 21 + off + sp;
      f32x4 acc[4] = {};
      #pragma unroll
      for (int kt = 0; kt < 8; ++kt){
        bf16x8 bfr = *reinterpret_cast<const bf16x8*>(smem + ((arow * 512 + kt * 64 + q4 * 16) ^ ((arow & 7) << 4)));
        #pragma unroll
        for (int ot = 0; ot < 4; ++ot){
          bf16x8 aw = *reinterpret_cast<const bf16x8*>(pk + (size_t)(((w * 4 + ot) * 8 + kt) * 64 + lane) * 8);
          acc[ot] = __builtin_amdgcn_mfma_f32_16x16x32_bf16(aw, bfr, acc[ot], 0, 0, 0);
        }
      }
      if (sv){
        const size_t grow = ((size_t)(b0 + bh) * 21 + off + sp) * 512;
        #pragma unroll
        for (int ot = 0; ot < 4; ++ot){
          const int ob = w * 64 + ot * 16 + q4 * 4;
          const f32x4 vb = *reinterpret_cast<const f32x4*>(bpp + ob);
          u32x2 pkv;
          pkv[0] = cvtpk(acc[ot][0] + vb[0], acc[ot][1] + vb[1]);
          pkv[1] = cvtpk(acc[ot][2] + vb[2], acc[ot][3] + vb[3]);
          *reinterpret_cast<u32x2*>(kvbuf + grow + ob) = pkv;
        }
      }
    }
  }
}

// ---------------------------------------------------------------------------
// K2: fused q-proj (swapped, in-place) + attention (R4-core, 4 passes x 2
// heads) + out-proj (swapped). 1 batch/block, 512 threads, LDS 48KB.
// Weight fragments register-preloaded far ahead of use (MLP > occupancy).
// [0,32768):      x -> q -> O, [token 64][ch 256] bf16 swz(row)
// [32768,36864):  K  [2 heads][32 slot][32 d] swz(slot)
// [36864,40960):  V^T[2 heads][32 d][32 slot] swz(d)
// [40960,49152):  P  [2 heads][64 tok][32 slot] swz(tok)
// ---------------------------------------------------------------------------
__global__ __launch_bounds__(512, 4) void k_attn(
    const float* __restrict__ x, const float* __restrict__ bq,
    const float* __restrict__ bproj, const uint16_t* __restrict__ ws,
    float* __restrict__ out)
{
  extern __shared__ char smem[];   // 49152 B
  const int t = threadIdx.x, lane = t & 63, w = t >> 6;
  const int q4 = lane >> 4, c15 = lane & 15;
  const size_t b = blockIdx.x;
  const uint16_t* wq_pk    = ws + WQ_PK;
  const uint16_t* wproj_pk = ws + WPROJ_PK;
  const uint16_t* kvbuf    = ws + KVBUF;

  // ---- preload ALL wq fragments (16 x 16B) — lands during x staging ----
  bf16x8 wf[2][8];
  #pragma unroll
  for (int mt = 0; mt < 2; ++mt)
    #pragma unroll
    for (int kt = 0; kt < 8; ++kt)
      wf[mt][kt] = *reinterpret_cast<const bf16x8*>(wq_pk + (size_t)(((w * 2 + mt) * 8 + kt) * 64 + lane) * 8);

  // ---- kv staging roles: unit = (head hh_s, kind); prefetch pass 0 ----
  const int dch = (t & 3) * 8, m = (t >> 2) & 31, unit = t >> 7;
  const int hh_s = unit >> 1, kind = unit & 1;
  const bool mv = m < 21;
  uint32_t sel = 0x05040100u;
  const uint16_t* rg = kvbuf;
  if (mv){
    int off, hw;
    if (m < 9)       { off = 0;  hw = 9; }
    else if (m < 13) { off = 9;  hw = 4; }
    else if (m < 17) { off = 13; hw = 4; }
    else             { off = 17; hw = 4; }
    const int ml = m - off;
    const int c2 = 2 * ml + kind;
    const int e = c2 >= hw ? 1 : 0, s = c2 - e * hw;
    sel = e ? 0x07060302u : 0x05040100u;
    rg = kvbuf + (b * 21 + off + s) * 512 + 2 * (hh_s * 32 + dch);  // pass0 head = hh_s
  }
  u16x8 L0 = {}, L1 = {};
  if (mv){
    L0 = *reinterpret_cast<const u16x8*>(rg);
    L1 = *reinterpret_cast<const u16x8*>(rg + 8);
  }

  // ---- stage x -> bf16 [64][256] swz (rows >=49 zeroed) ----
  {
    const int r = t >> 3, c0 = (t & 7) * 32;
    u16x8 vv[4] = {};
    if (r < 49){
      const float* src = x + (b * 49 + r) * 256 + c0;
      #pragma unroll
      for (int jj = 0; jj < 4; ++jj){
        f32x4 f0 = *reinterpret_cast<const f32x4*>(src + jj * 8);
        f32x4 f1 = *reinterpret_cast<const f32x4*>(src + jj * 8 + 4);
        union { u16x8 v; uint32_t d[4]; } R;
        R.d[0] = cvtpk(f0[0], f0[1]);
        R.d[1] = cvtpk(f0[2], f0[3]);
        R.d[2] = cvtpk(f1[0], f1[1]);
        R.d[3] = cvtpk(f1[2], f1[3]);
        vv[jj] = R.v;
      }
    }
    #pragma unroll
    for (int jj = 0; jj < 4; ++jj)
      *reinterpret_cast<u16x8*>(smem + ((r * 512 + c0 * 2 + jj * 16) ^ ((r & 7) << 4))) = vv[jj];
  }
  __syncthreads();

  // ---- q-proj swapped: q^T[o][token] = Wq * x^T (weights in registers) ----
  f32x4 qacc[2][4] = {};
  #pragma unroll
  for (int kt = 0; kt < 8; ++kt){
    bf16x8 bx[4];
    #pragma unroll
    for (int nt = 0; nt < 4; ++nt){
      const int row = nt * 16 + c15;
      bx[nt] = *reinterpret_cast<const bf16x8*>(smem + ((row * 512 + kt * 64 + q4 * 16) ^ ((row & 7) << 4)));
    }
    #pragma unroll
    for (int mt = 0; mt < 2; ++mt)
      #pragma unroll
      for (int nt = 0; nt < 4; ++nt)
        qacc[mt][nt] = __builtin_amdgcn_mfma_f32_16x16x32_bf16(wf[mt][kt], bx[nt], qacc[mt][nt], 0, 0, 0);
  }
  __syncthreads();   // ALL x reads complete -> region reusable

  // q epilogue IN-PLACE into x region: [token][ch] = (q + bq) * SCALE_Q
  #pragma unroll
  for (int mt = 0; mt < 2; ++mt){
    const int ob = w * 32 + mt * 16 + q4 * 4;
    const f32x4 vb = *reinterpret_cast<const f32x4*>(bq + ob);
    #pragma unroll
    for (int nt = 0; nt < 4; ++nt){
      const int row = nt * 16 + c15;
      u32x2 pkq;
      pkq[0] = cvtpk((qacc[mt][nt][0] + vb[0]) * SCALE_Q, (qacc[mt][nt][1] + vb[1]) * SCALE_Q);
      pkq[1] = cvtpk((qacc[mt][nt][2] + vb[2]) * SCALE_Q, (qacc[mt][nt][3] + vb[3]) * SCALE_Q);
      *reinterpret_cast<u32x2*>(smem + ((row * 512 + ob * 2) ^ ((row & 7) << 4))) = pkq;
    }
  }

  // ---- preload ALL wproj fragments now — lands during attention ----
  bf16x8 pf[2][8];
  #pragma unroll
  for (int mt = 0; mt < 2; ++mt)
    #pragma unroll
    for (int kt = 0; kt < 8; ++kt)
      pf[mt][kt] = *reinterpret_cast<const bf16x8*>(wproj_pk + (size_t)(((w * 2 + mt) * 8 + kt) * 64 + lane) * 8);

  __syncthreads();   // q visible

  // ---- attention: 4 passes x 2 heads, 4 waves/head (16 qrows each) ----
  const int hh = w >> 2, wh2 = w & 3;
  for (int p = 0; p < 4; ++p){
    { // write prefetched kv regs -> LDS
      u16x8 vfr = {};
      if (mv) vfr = extract_par(L0, L1, sel);
      if (kind == 0){
        *reinterpret_cast<u16x8*>(smem + 32768 + hh_s * 2048 + ((m * 64 + dch * 2) ^ ((m & 7) << 4))) = vfr;
      } else {
        #pragma unroll
        for (int jj = 0; jj < 8; ++jj){
          const int d = dch + jj;
          *reinterpret_cast<uint16_t*>(smem + 36864 + hh_s * 2048 + ((d * 64 + m * 2) ^ ((d & 7) << 4))) = vfr[jj];
        }
      }
      if (p < 3 && mv){  // prefetch next pass (heads +2 -> +128 elems)
        L0 = *reinterpret_cast<const u16x8*>(rg + (p + 1) * 128);
        L1 = *reinterpret_cast<const u16x8*>(rg + (p + 1) * 128 + 8);
      }
    }
    __syncthreads();

    const int hcolb = (p * 2 + hh) * 64;         // head byte-col in q/O region
    const int kbK = 32768 + hh * 2048;
    const int kbV = 36864 + hh * 2048;
    const int pb  = 40960 + hh * 4096;

    // scores (normal): A=q rows (16 tokens), B=K cols (32 slots), K=32 dims
    const int arowq = wh2 * 16 + c15;
    bf16x8 aq = *reinterpret_cast<const bf16x8*>(smem + ((arowq * 512 + hcolb + q4 * 16) ^ ((arowq & 7) << 4)));
    f32x4 sacc[2];
    #pragma unroll
    for (int nt = 0; nt < 2; ++nt){
      const int m0 = nt * 16 + c15;
      bf16x8 bk = *reinterpret_cast<const bf16x8*>(smem + kbK + ((m0 * 64 + q4 * 16) ^ ((m0 & 7) << 4)));
      f32x4 z = {};
      sacc[nt] = __builtin_amdgcn_mfma_f32_16x16x32_bf16(aq, bk, z, 0, 0, 0);
    }
    // softmax (21 valid slots) in C-frag layout; P -> LDS (pads written 0)
    const bool ok1 = c15 < 5;
    #pragma unroll
    for (int i = 0; i < 4; ++i){
      const float s0 = sacc[0][i];
      const float s1 = sacc[1][i];
      float mx = fmaxf(s0, ok1 ? s1 : -3.0e38f);
      #pragma unroll
      for (int dd = 1; dd < 16; dd <<= 1) mx = fmaxf(mx, __shfl_xor(mx, dd));
      const float e0 = __expf(s0 - mx);
      const float e1 = ok1 ? __expf(s1 - mx) : 0.f;
      float sm = e0 + e1;
      #pragma unroll
      for (int dd = 1; dd < 16; dd <<= 1) sm += __shfl_xor(sm, dd);
      const float inv = 1.0f / sm;
      const int pr = wh2 * 16 + q4 * 4 + i;
      *reinterpret_cast<uint16_t*>(smem + pb + ((pr * 64 + c15 * 2) ^ ((pr & 7) << 4))) = f2bf(e0 * inv);
      *reinterpret_cast<uint16_t*>(smem + pb + ((pr * 64 + (c15 + 16) * 2) ^ ((pr & 7) << 4))) = f2bf(e1 * inv);
    }
    // PV (normal): A=P rows (16 tokens, own rows), B=V^T cols (32 dims), K=32 slots
    const int prow = wh2 * 16 + c15;
    bf16x8 ap = *reinterpret_cast<const bf16x8*>(smem + pb + ((prow * 64 + q4 * 16) ^ ((prow & 7) << 4)));
    f32x4 oacc[2];
    #pragma unroll
    for (int nt = 0; nt < 2; ++nt){
      const int d0 = nt * 16 + c15;
      bf16x8 bv = *reinterpret_cast<const bf16x8*>(smem + kbV + ((d0 * 64 + q4 * 16) ^ ((d0 & 7) << 4)));
      f32x4 z = {};
      oacc[nt] = __builtin_amdgcn_mfma_f32_16x16x32_bf16(ap, bv, z, 0, 0, 0);
    }
    // O -> q/O region in-place (own head cols, own row band)
    #pragma unroll
    for (int nt = 0; nt < 2; ++nt)
      #pragma unroll
      for (int i = 0; i < 4; ++i){
        const int row = wh2 * 16 + q4 * 4 + i;
        const int colb = hcolb + (nt * 16 + c15) * 2;
        *reinterpret_cast<uint16_t*>(smem + ((row * 512 + colb) ^ ((row & 7) << 4))) = f2bf(oacc[nt][i]);
      }
    __syncthreads();
  }

  // ---- out-proj swapped: out^T[o][token] = Wproj * O^T (weights in regs) ----
  f32x4 pacc[2][4] = {};
  #pragma unroll
  for (int kt = 0; kt < 8; ++kt){
    bf16x8 bo[4];
    #pragma unroll
    for (int nt = 0; nt < 4; ++nt){
      const int row = nt * 16 + c15;
      bo[nt] = *reinterpret_cast<const bf16x8*>(smem + ((row * 512 + kt * 64 + q4 * 16) ^ ((row & 7) << 4)));
    }
    #pragma unroll
    for (int mt = 0; mt < 2; ++mt)
      #pragma unroll
      for (int nt = 0; nt < 4; ++nt)
        pacc[mt][nt] = __builtin_amdgcn_mfma_f32_16x16x32_bf16(pf[mt][kt], bo[nt], pacc[mt][nt], 0, 0, 0);
  }
  #pragma unroll
  for (int mt = 0; mt < 2; ++mt){
    const int ob = w * 32 + mt * 16 + q4 * 4;
    const f32x4 vb = *reinterpret_cast<const f32x4*>(bproj + ob);
    #pragma unroll
    for (int nt = 0; nt < 4; ++nt){
      const int n = nt * 16 + c15;
      if (n < 49)
        *reinterpret_cast<f32x4*>(out + (b * 49 + n) * 256 + ob) = pacc[mt][nt] + vb;
    }
  }
}

// ---------------------------------------------------------------------------
extern "C" void kernel_launch(void* const* d_in, const int* in_sizes, int n_in,
                              void* d_out, int out_size, void* d_ws, size_t ws_size,
                              hipStream_t stream)
{
  const float* x     = (const float*)d_in[0];
  const float* wq    = (const float*)d_in[1];
  const float* bq    = (const float*)d_in[2];
  const float* wd1   = (const float*)d_in[3];
  const float* bd1   = (const float*)d_in[4];
  const float* wp1   = (const float*)d_in[5];
  const float* bp1   = (const float*)d_in[6];
  const float* wd2   = (const float*)d_in[7];
  const float* bd2   = (const float*)d_in[8];
  const float* wp2   = (const float*)d_in[9];
  const float* bp2   = (const float*)d_in[10];
  const float* wd3   = (const float*)d_in[11];
  const float* bd3   = (const float*)d_in[12];
  const float* wp3   = (const float*)d_in[13];
  const float* bp3   = (const float*)d_in[14];
  const float* wd4   = (const float*)d_in[15];
  const float* bd4   = (const float*)d_in[16];
  const float* wp4   = (const float*)d_in[17];
  const float* bp4   = (const float*)d_in[18];
  const float* wproj = (const float*)d_in[19];
  const float* bproj = (const float*)d_in[20];
  uint16_t* ws = (uint16_t*)d_ws;
  float* out = (float*)d_out;

  k_prepack<<<320, 256, 0, stream>>>(wq, wp1, wp2, wp3, wp4, wproj, ws);
  k_kv<<<512, 512, 86016, stream>>>(x, wd1, bd1, bp1, wd2, bd2, bp2,
                                    wd3, bd3, bp3, wd4, bd4, bp4,
                                    ws, ws + KVBUF);
  k_attn<<<4096, 512, 49152, stream>>>(x, bq, bproj, ws, out);
}

// Round 10
// 294.352 us; speedup vs baseline: 1.6557x; 1.6557x over previous
//
#include <hip/hip_runtime.h>
#include <stdint.h>

typedef __attribute__((ext_vector_type(8))) short bf16x8;
typedef __attribute__((ext_vector_type(8))) unsigned short u16x8;
typedef __attribute__((ext_vector_type(4))) float f32x4;
typedef __attribute__((ext_vector_type(2))) uint32_t u32x2;

#define DEV __device__ __forceinline__

// ws layout in ushort elements
constexpr size_t WQ_PK    = 0;         // 65536 elems
constexpr size_t WPROJ_PK = 65536;     // 65536 elems
constexpr size_t WP_PK    = 131072;    // 4 * 131072 elems
constexpr size_t KVBUF    = 655360;    // 4096*21*512 = 44040192 elems
// kvbuf layout: [b][row 0..20][o 0..511] bf16, producer-coalesced.

constexpr float SCALE_Q  = 0.17677669529663687f;              // 32^-0.5
constexpr float SCALE_Q2 = SCALE_Q * 1.4426950408889634f;     // fold log2(e): softmax in exp2 domain

DEV uint16_t f2bf(float f){
  uint32_t u = __builtin_bit_cast(uint32_t, f);
  u += 0x7fffu + ((u >> 16) & 1u);
  return (uint16_t)(u >> 16);
}

DEV uint32_t cvtpk(float a, float b){
  uint32_t r;
  asm("v_cvt_pk_bf16_f32 %0, %1, %2" : "=v"(r) : "v"(a), "v"(b));
  return r;
}

// out[j] = (j<4 ? a[2j+par] : b[2(j-4)+par]) via byte-perm selector
DEV u16x8 extract_par(u16x8 a, u16x8 b, uint32_t sel){
  union U { u16x8 v; uint32_t d[4]; } A, B, R;
  A.v = a; B.v = b;
  R.d[0] = __builtin_amdgcn_perm(A.d[1], A.d[0], sel);
  R.d[1] = __builtin_amdgcn_perm(A.d[3], A.d[2], sel);
  R.d[2] = __builtin_amdgcn_perm(B.d[1], B.d[0], sel);
  R.d[3] = __builtin_amdgcn_perm(B.d[3], B.d[2], sel);
  return R.v;
}

// ---------------------------------------------------------------------------
// K0: prepack weights into MFMA fragment layout, f32 -> bf16.
// frag (nt,kt): lane l, j supplies W[n=nt*16+(l&15)][k=kt*32+(l>>4)*8+j].
// ---------------------------------------------------------------------------
__global__ __launch_bounds__(256) void k_prepack(
    const float* __restrict__ wq,  const float* __restrict__ wp1,
    const float* __restrict__ wp2, const float* __restrict__ wp3,
    const float* __restrict__ wp4, const float* __restrict__ wproj,
    uint16_t* __restrict__ ws)
{
  int f = blockIdx.x * 256 + threadIdx.x;   // 0..81919 fragment id
  const float* src; uint16_t* dst; int g;
  if (f < 8192)       { src = wq;    dst = ws + WQ_PK;    g = f; }
  else if (f < 16384) { src = wproj; dst = ws + WPROJ_PK; g = f - 8192; }
  else {
    int j = (f - 16384) >> 14;
    src = j == 0 ? wp1 : j == 1 ? wp2 : j == 2 ? wp3 : wp4;
    dst = ws + WP_PK + (size_t)j * 131072;
    g = (f - 16384) & 16383;
  }
  int l = g & 63, kt = (g >> 6) & 7, nt = g >> 9;
  int n  = nt * 16 + (l & 15);
  int k0 = kt * 32 + (l >> 4) * 8;
  const float* s = src + (size_t)n * 256 + k0;
  u16x8 v;
  #pragma unroll
  for (int j = 0; j < 8; ++j) v[j] = f2bf(s[j]);
  *reinterpret_cast<u16x8*>(dst + (size_t)g * 8) = v;
}

// ---------------------------------------------------------------------------
// K1 (R4-verified fastest variant): depthwise convs + pointwise (normal MFMA)
// -> kvbuf2[b][row][o] (bf16). 8 batches/block, 512 threads. LDS 86016 B.
// dT [168][256] ushort, swizzled: byte = (row*512 + c*2) ^ ((row&7)<<4)
// ---------------------------------------------------------------------------
__global__ __launch_bounds__(512, 2) void k_kv(
    const float* __restrict__ x,
    const float* __restrict__ wd1, const float* __restrict__ bd1, const float* __restrict__ bp1,
    const float* __restrict__ wd2, const float* __restrict__ bd2, const float* __restrict__ bp2,
    const float* __restrict__ wd3, const float* __restrict__ bd3, const float* __restrict__ bp3,
    const float* __restrict__ wd4, const float* __restrict__ bd4, const float* __restrict__ bp4,
    const uint16_t* __restrict__ ws, uint16_t* __restrict__ kvbuf)
{
  extern __shared__ char smem[];  // 86016 B
  const int t = threadIdx.x, lane = t & 63, w = t >> 6;
  const int b0 = blockIdx.x * 8;

  constexpr int DILA[4] = {1,2,3,4}, PADA[4] = {0,0,1,2}, OWA[4] = {3,2,2,2};
  constexpr int HWA[4]  = {9,4,4,4}, OFFA[4] = {0,9,13,17}, MTA[4] = {5,2,2,2};

  // ---- depthwise conv, all branches; write dT (bf16) to LDS ----
  {
    const int c = t & 255, half = t >> 8;
    for (int pass = 0; pass < 4; ++pass){
      const int bh = pass * 2 + half;
      float xr[49];
      #pragma unroll
      for (int p = 0; p < 49; ++p)
        xr[p] = x[((size_t)(b0 + bh) * 49 + p) * 256 + c];
      #pragma unroll
      for (int j = 0; j < 4; ++j){
        const float* wdp = j==0?wd1:j==1?wd2:j==2?wd3:wd4;
        const float* bdp = j==0?bd1:j==1?bd2:j==2?bd3:bd4;
        float wv[9];
        #pragma unroll
        for (int q = 0; q < 9; ++q) wv[q] = wdp[c * 9 + q];
        const float bdv = bdp[c];
        #pragma unroll
        for (int oy = 0; oy < OWA[j]; ++oy)
        #pragma unroll
        for (int ox = 0; ox < OWA[j]; ++ox){
          float acc = bdv;
          #pragma unroll
          for (int ky = 0; ky < 3; ++ky){
            const int yy = oy * 2 - PADA[j] + ky * DILA[j];
            if (yy < 0 || yy > 6) continue;
            #pragma unroll
            for (int kx = 0; kx < 3; ++kx){
              const int xx = ox * 2 - PADA[j] + kx * DILA[j];
              if (xx < 0 || xx > 6) continue;
              acc += xr[yy * 7 + xx] * wv[ky * 3 + kx];
            }
          }
          const int row = bh * 21 + OFFA[j] + oy * OWA[j] + ox;
          *reinterpret_cast<uint16_t*>(smem + ((row * 512 + c * 2) ^ ((row & 7) << 4))) = f2bf(acc);
        }
      }
    }
  }
  __syncthreads();

  // ---- pointwise GEMM per branch (normal); coalesced 2B stores ----
  // wave w owns output cols [w*64, w*64+64)
  #pragma unroll
  for (int j = 0; j < 4; ++j){
    const uint16_t* pk = ws + WP_PK + (size_t)j * 131072;
    const float* bpp = j==0?bp1:j==1?bp2:j==2?bp3:bp4;
    const int hw = HWA[j], off = OFFA[j], MV = hw * 8;
    float bpv[4];
    #pragma unroll
    for (int nt = 0; nt < 4; ++nt) bpv[nt] = bpp[w * 64 + nt * 16 + (lane & 15)];
    for (int mt = 0; mt < MTA[j]; ++mt){
      f32x4 acc[4] = {};
      const int mrow = mt * 16 + (lane & 15);
      const bool av = mrow < MV;
      const int bh = mrow / hw, s = mrow - bh * hw;
      const int arow = bh * 21 + off + s;
      const int abase = arow * 512 + (lane >> 4) * 16;
      #pragma unroll
      for (int kt = 0; kt < 8; ++kt){
        bf16x8 a = {};
        if (av) a = *reinterpret_cast<const bf16x8*>(smem + ((abase + kt * 64) ^ ((arow & 7) << 4)));
        #pragma unroll
        for (int nt = 0; nt < 4; ++nt){
          const int ntg = w * 4 + nt;
          bf16x8 bfr = *reinterpret_cast<const bf16x8*>(pk + (size_t)((ntg * 8 + kt) * 64 + lane) * 8);
          acc[nt] = __builtin_amdgcn_mfma_f32_16x16x32_bf16(a, bfr, acc[nt], 0, 0, 0);
        }
      }
      const int mr2 = mt * 16 + (lane >> 4) * 4;
      #pragma unroll
      for (int i = 0; i < 4; ++i){
        const int m = mr2 + i;
        if (m >= MV) continue;
        const int bh2 = m / hw, s2 = m - bh2 * hw;
        const size_t grow = ((size_t)(b0 + bh2) * 21 + off + s2) * 512;
        #pragma unroll
        for (int nt = 0; nt < 4; ++nt)
          kvbuf[grow + w * 64 + nt * 16 + (lane & 15)] = f2bf(acc[nt][i] + bpv[nt]);
      }
    }
  }
}

// ---------------------------------------------------------------------------
// K2: q-proj (swapped, packed epilogue — R7-verified) + attention (R4-verified
// core, exp2 softmax) + out-proj (R4-verified normal, coalesced stores).
// 1 batch/block, 512 threads (8 waves), LDS 64 KB -> 2 blocks/CU.
// R0 [0,32768): x bf16 [64][256] swz; reused per attention pass:
//   KS 4x2KB @0, VT 4x2KB @8192, PA 4x4KB @16384.
// R1 [32768,65536): q/O [token 64][ch 256] bf16 swz.
// ---------------------------------------------------------------------------
__global__ __launch_bounds__(512, 4) void k_attn(
    const float* __restrict__ x, const float* __restrict__ bq,
    const float* __restrict__ bproj, const uint16_t* __restrict__ ws,
    float* __restrict__ out)
{
  extern __shared__ char smem[];   // 65536 B
  constexpr int OSB = 32768;
  const int t = threadIdx.x, lane = t & 63, w = t >> 6;
  const int q4 = lane >> 4, c15 = lane & 15;
  const size_t b = blockIdx.x;
  const uint16_t* wq_pk    = ws + WQ_PK;
  const uint16_t* wproj_pk = ws + WPROJ_PK;
  const uint16_t* kvbuf    = ws + KVBUF;

  // ---- kv prefetch (pass 0) ----
  const int sh4 = t >> 7, m = (t >> 2) & 31, dch = (t & 3) * 8;
  const bool mv = m < 21;
  uint32_t selK = 0x05040100u, selV = 0x05040100u;
  const uint16_t *rk = kvbuf, *rv = kvbuf;
  if (mv){
    int off, hw;
    if (m < 9)       { off = 0;  hw = 9; }
    else if (m < 13) { off = 9;  hw = 4; }
    else if (m < 17) { off = 13; hw = 4; }
    else             { off = 17; hw = 4; }
    const int ml = m - off;
    const int c2k = 2 * ml,     ek = c2k >= hw ? 1 : 0, sk = c2k - ek * hw;
    const int c2v = 2 * ml + 1, ev = c2v >= hw ? 1 : 0, sv = c2v - ev * hw;
    selK = ek ? 0x07060302u : 0x05040100u;
    selV = ev ? 0x07060302u : 0x05040100u;
    const int o0 = 2 * (sh4 * 32 + dch);   // pass0 head = sh4
    rk = kvbuf + (b * 21 + off + sk) * 512 + o0;
    rv = kvbuf + (b * 21 + off + sv) * 512 + o0;
  }
  u16x8 L0 = {}, L1 = {}, L2 = {}, L3 = {};
  if (mv){
    L0 = *reinterpret_cast<const u16x8*>(rk);
    L1 = *reinterpret_cast<const u16x8*>(rk + 8);
    L2 = *reinterpret_cast<const u16x8*>(rv);
    L3 = *reinterpret_cast<const u16x8*>(rv + 8);
  }

  // ---- stage x -> bf16 [64][256] swz (rows >=49 zeroed) ----
  {
    const int r = t >> 3, c0 = (t & 7) * 32;
    u16x8 vv[4] = {};
    if (r < 49){
      const float* src = x + (b * 49 + r) * 256 + c0;
      #pragma unroll
      for (int jj = 0; jj < 4; ++jj){
        f32x4 f0 = *reinterpret_cast<const f32x4*>(src + jj * 8);
        f32x4 f1 = *reinterpret_cast<const f32x4*>(src + jj * 8 + 4);
        union { u16x8 v; uint32_t d[4]; } R;
        R.d[0] = cvtpk(f0[0], f0[1]);
        R.d[1] = cvtpk(f0[2], f0[3]);
        R.d[2] = cvtpk(f1[0], f1[1]);
        R.d[3] = cvtpk(f1[2], f1[3]);
        vv[jj] = R.v;
      }
    }
    #pragma unroll
    for (int jj = 0; jj < 4; ++jj)
      *reinterpret_cast<u16x8*>(smem + ((r * 512 + c0 * 2 + jj * 16) ^ ((r & 7) << 4))) = vv[jj];
  }
  __syncthreads();

  // ---- q-proj swapped (R7-verified): q^T[o][token] = Wq * x^T ----
  f32x4 qacc[2][4] = {};
  #pragma unroll 2
  for (int kt = 0; kt < 8; ++kt){
    bf16x8 bx[4];
    #pragma unroll
    for (int nt = 0; nt < 4; ++nt){
      const int row = nt * 16 + c15;
      bx[nt] = *reinterpret_cast<const bf16x8*>(smem + ((row * 512 + kt * 64 + q4 * 16) ^ ((row & 7) << 4)));
    }
    #pragma unroll
    for (int mt = 0; mt < 2; ++mt){
      bf16x8 aw = *reinterpret_cast<const bf16x8*>(wq_pk + (size_t)(((w * 2 + mt) * 8 + kt) * 64 + lane) * 8);
      #pragma unroll
      for (int nt = 0; nt < 4; ++nt)
        qacc[mt][nt] = __builtin_amdgcn_mfma_f32_16x16x32_bf16(aw, bx[nt], qacc[mt][nt], 0, 0, 0);
    }
  }
  // q epilogue: packed b64 writes, R1[token][ch] = (q + bq) * SCALE_Q2 (exp2 domain)
  #pragma unroll
  for (int mt = 0; mt < 2; ++mt){
    const int ob = w * 32 + mt * 16 + q4 * 4;
    const f32x4 vb = *reinterpret_cast<const f32x4*>(bq + ob);
    #pragma unroll
    for (int nt = 0; nt < 4; ++nt){
      const int row = nt * 16 + c15;
      u32x2 pkq;
      pkq[0] = cvtpk((qacc[mt][nt][0] + vb[0]) * SCALE_Q2, (qacc[mt][nt][1] + vb[1]) * SCALE_Q2);
      pkq[1] = cvtpk((qacc[mt][nt][2] + vb[2]) * SCALE_Q2, (qacc[mt][nt][3] + vb[3]) * SCALE_Q2);
      *reinterpret_cast<u32x2*>(smem + OSB + ((row * 512 + ob * 2) ^ ((row & 7) << 4))) = pkq;
    }
  }
  __syncthreads();   // x consumed; q visible; R0 free for KS/VT/PA

  // ---- attention: R4-verified core. 2 passes x 4 heads, 2 waves/head ----
  for (int p = 0; p < 2; ++p){
    { // extract prefetched kv -> KS (vector) / VT (transposed scatter)
      u16x8 kf = extract_par(L0, L1, selK);
      u16x8 vf = extract_par(L2, L3, selV);
      *reinterpret_cast<u16x8*>(smem + sh4 * 2048 + ((m * 64 + dch * 2) ^ ((m & 7) << 4))) = kf;
      #pragma unroll
      for (int jj = 0; jj < 8; ++jj){
        const int d = dch + jj;
        *reinterpret_cast<uint16_t*>(smem + 8192 + sh4 * 2048 + ((d * 64 + m * 2) ^ ((d & 7) << 4))) = vf[jj];
      }
      if (p == 0 && mv){  // prefetch pass-1 (head = 4+sh4 -> +256 elems)
        L0 = *reinterpret_cast<const u16x8*>(rk + 256);
        L1 = *reinterpret_cast<const u16x8*>(rk + 264);
        L2 = *reinterpret_cast<const u16x8*>(rv + 256);
        L3 = *reinterpret_cast<const u16x8*>(rv + 264);
      }
    }
    __syncthreads();

    const int h4 = w >> 1, wh = w & 1;
    const int hcol = (p * 4 + h4) * 64;   // head byte col in R1
    const int pabase = 16384 + h4 * 4096;

    // scores (normal): M=32 rows (2 mt), N=32 slots (2 nt), K=32 dims
    bf16x8 bk[2];
    #pragma unroll
    for (int nt = 0; nt < 2; ++nt){
      const int m0 = nt * 16 + c15;
      bk[nt] = *reinterpret_cast<const bf16x8*>(smem + h4 * 2048 + ((m0 * 64 + q4 * 16) ^ ((m0 & 7) << 4)));
    }
    f32x4 sacc[2][2];
    #pragma unroll
    for (int mt = 0; mt < 2; ++mt){
      const int row = wh * 32 + mt * 16 + c15;
      bf16x8 aq = *reinterpret_cast<const bf16x8*>(smem + OSB + ((row * 512 + hcol + q4 * 16) ^ ((row & 7) << 4)));
      #pragma unroll
      for (int nt = 0; nt < 2; ++nt){
        f32x4 z = {};
        sacc[mt][nt] = __builtin_amdgcn_mfma_f32_16x16x32_bf16(aq, bk[nt], z, 0, 0, 0);
      }
    }
    // softmax (21 valid slots) in C-frag layout, exp2 domain; P -> PA
    const bool ok1 = c15 < 5;
    #pragma unroll
    for (int mt = 0; mt < 2; ++mt)
      #pragma unroll
      for (int i = 0; i < 4; ++i){
        const float s0 = sacc[mt][0][i];
        const float s1 = sacc[mt][1][i];
        float mx = fmaxf(s0, ok1 ? s1 : -3.0e38f);
        #pragma unroll
        for (int dd = 1; dd < 16; dd <<= 1) mx = fmaxf(mx, __shfl_xor(mx, dd));
        const float e0 = exp2f(s0 - mx);
        const float e1 = ok1 ? exp2f(s1 - mx) : 0.f;
        float sm = e0 + e1;
        #pragma unroll
        for (int dd = 1; dd < 16; dd <<= 1) sm += __shfl_xor(sm, dd);
        const float inv = 1.0f / sm;
        const int pr = wh * 32 + mt * 16 + q4 * 4 + i;
        *reinterpret_cast<uint16_t*>(smem + pabase + ((pr * 64 + c15 * 2) ^ ((pr & 7) << 4))) = f2bf(e0 * inv);
        *reinterpret_cast<uint16_t*>(smem + pabase + ((pr * 64 + (c15 + 16) * 2) ^ ((pr & 7) << 4))) = f2bf(e1 * inv);
      }
    // PV (normal): M=32 rows, N=32 dims, K=32 slots (pads zero)
    f32x4 oacc[2][2];
    #pragma unroll
    for (int mt = 0; mt < 2; ++mt){
      const int pr = wh * 32 + mt * 16 + c15;
      bf16x8 ap = *reinterpret_cast<const bf16x8*>(smem + pabase + ((pr * 64 + q4 * 16) ^ ((pr & 7) << 4)));
      #pragma unroll
      for (int nt = 0; nt < 2; ++nt){
        const int d0 = nt * 16 + c15;
        bf16x8 bv = *reinterpret_cast<const bf16x8*>(smem + 8192 + h4 * 2048 + ((d0 * 64 + q4 * 16) ^ ((d0 & 7) << 4)));
        f32x4 z = {};
        oacc[mt][nt] = __builtin_amdgcn_mfma_f32_16x16x32_bf16(ap, bv, z, 0, 0, 0);
      }
    }
    // O -> R1 (own head cols, scalar writes as in R4)
    #pragma unroll
    for (int mt = 0; mt < 2; ++mt)
      #pragma unroll
      for (int nt = 0; nt < 2; ++nt)
        #pragma unroll
        for (int i = 0; i < 4; ++i){
          const int row = wh * 32 + mt * 16 + q4 * 4 + i;
          const int colb = hcol + (nt * 16 + c15) * 2;
          *reinterpret_cast<uint16_t*>(smem + OSB + ((row * 512 + colb) ^ ((row & 7) << 4))) = f2bf(oacc[mt][nt][i]);
        }
    __syncthreads();
  }

  // ---- out-proj (R4-verified normal): B-frags from global, coalesced stores ----
  f32x4 pacc[4][2] = {};
  #pragma unroll 2
  for (int kt = 0; kt < 8; ++kt){
    bf16x8 a[4];
    #pragma unroll
    for (int mt = 0; mt < 4; ++mt){
      const int row = mt * 16 + c15;
      a[mt] = *reinterpret_cast<const bf16x8*>(smem + OSB + ((row * 512 + kt * 64 + q4 * 16) ^ ((row & 7) << 4)));
    }
    #pragma unroll
    for (int nt = 0; nt < 2; ++nt){
      bf16x8 bfr = *reinterpret_cast<const bf16x8*>(wproj_pk + (size_t)(((w * 2 + nt) * 8 + kt) * 64 + lane) * 8);
      #pragma unroll
      for (int mt = 0; mt < 4; ++mt)
        pacc[mt][nt] = __builtin_amdgcn_mfma_f32_16x16x32_bf16(a[mt], bfr, pacc[mt][nt], 0, 0, 0);
    }
  }
  #pragma unroll
  for (int nt = 0; nt < 2; ++nt){
    const int col = w * 32 + nt * 16 + c15;
    const float bpv = bproj[col];
    #pragma unroll
    for (int mt = 0; mt < 4; ++mt)
      #pragma unroll
      for (int i = 0; i < 4; ++i){
        const int n = mt * 16 + q4 * 4 + i;
        if (n < 49)
          out[(b * 49 + n) * 256 + col] = pacc[mt][nt][i] + bpv;
      }
  }
}

// ---------------------------------------------------------------------------
extern "C" void kernel_launch(void* const* d_in, const int* in_sizes, int n_in,
                              void* d_out, int out_size, void* d_ws, size_t ws_size,
                              hipStream_t stream)
{
  const float* x     = (const float*)d_in[0];
  const float* wq    = (const float*)d_in[1];
  const float* bq    = (const float*)d_in[2];
  const float* wd1   = (const float*)d_in[3];
  const float* bd1   = (const float*)d_in[4];
  const float* wp1   = (const float*)d_in[5];
  const float* bp1   = (const float*)d_in[6];
  const float* wd2   = (const float*)d_in[7];
  const float* bd2   = (const float*)d_in[8];
  const float* wp2   = (const float*)d_in[9];
  const float* bp2   = (const float*)d_in[10];
  const float* wd3   = (const float*)d_in[11];
  const float* bd3   = (const float*)d_in[12];
  const float* wp3   = (const float*)d_in[13];
  const float* bp3   = (const float*)d_in[14];
  const float* wd4   = (const float*)d_in[15];
  const float* bd4   = (const float*)d_in[16];
  const float* wp4   = (const float*)d_in[17];
  const float* bp4   = (const float*)d_in[18];
  const float* wproj = (const float*)d_in[19];
  const float* bproj = (const float*)d_in[20];
  uint16_t* ws = (uint16_t*)d_ws;
  float* out = (float*)d_out;

  k_prepack<<<320, 256, 0, stream>>>(wq, wp1, wp2, wp3, wp4, wproj, ws);
  k_kv<<<512, 512, 86016, stream>>>(x, wd1, bd1, bp1, wd2, bd2, bp2,
                                    wd3, bd3, bp3, wd4, bd4, bp4,
                                    ws, ws + KVBUF);
  k_attn<<<4096, 512, 65536, stream>>>(x, bq, bproj, ws, out);
}

// Round 12
// 282.071 us; speedup vs baseline: 1.7278x; 1.0435x over previous
//
#include <hip/hip_runtime.h>
#include <stdint.h>

typedef __attribute__((ext_vector_type(8))) short bf16x8;
typedef __attribute__((ext_vector_type(8))) unsigned short u16x8;
typedef __attribute__((ext_vector_type(4))) float f32x4;
typedef __attribute__((ext_vector_type(2))) uint32_t u32x2;

#define DEV __device__ __forceinline__

// ws layout in ushort elements
constexpr size_t WQ_PK    = 0;         // 65536 elems
constexpr size_t WPROJ_PK = 65536;     // 65536 elems
constexpr size_t WP_PK    = 131072;    // 4 * 131072 elems
constexpr size_t KVBUF    = 655360;    // 4096*21*512 = 44040192 elems
// kvbuf layout: [b][row 0..20 (concat spatial)][o 0..511] bf16 — producer-
// coalesced. Gather permute to (kind,head,slot,dim) happens in k_attn staging
// via stride-2 parity extraction (v_perm) of 32B vector loads.

constexpr float SCALE_Q  = 0.17677669529663687f;              // 32^-0.5
constexpr float SCALE_Q2 = SCALE_Q * 1.4426950408889634f;     // fold log2(e): softmax in exp2 domain

DEV uint16_t f2bf(float f){
  uint32_t u = __builtin_bit_cast(uint32_t, f);
  u += 0x7fffu + ((u >> 16) & 1u);
  return (uint16_t)(u >> 16);
}

DEV uint32_t cvtpk(float a, float b){
  uint32_t r;
  asm("v_cvt_pk_bf16_f32 %0, %1, %2" : "=v"(r) : "v"(a), "v"(b));
  return r;
}

// out[j] = (j<4 ? a[2j+par] : b[2(j-4)+par]) via byte-perm selector
DEV u16x8 extract_par(u16x8 a, u16x8 b, uint32_t sel){
  union U { u16x8 v; uint32_t d[4]; } A, B, R;
  A.v = a; B.v = b;
  R.d[0] = __builtin_amdgcn_perm(A.d[1], A.d[0], sel);
  R.d[1] = __builtin_amdgcn_perm(A.d[3], A.d[2], sel);
  R.d[2] = __builtin_amdgcn_perm(B.d[1], B.d[0], sel);
  R.d[3] = __builtin_amdgcn_perm(B.d[3], B.d[2], sel);
  return R.v;
}

// ---------------------------------------------------------------------------
// K0: prepack weights into MFMA fragment layout, f32 -> bf16.
// frag (nt,kt): lane l, j supplies W[n=nt*16+(l&15)][k=kt*32+(l>>4)*8+j].
// ---------------------------------------------------------------------------
__global__ __launch_bounds__(256) void k_prepack(
    const float* __restrict__ wq,  const float* __restrict__ wp1,
    const float* __restrict__ wp2, const float* __restrict__ wp3,
    const float* __restrict__ wp4, const float* __restrict__ wproj,
    uint16_t* __restrict__ ws)
{
  int f = blockIdx.x * 256 + threadIdx.x;   // 0..81919 fragment id
  const float* src; uint16_t* dst; int g;
  if (f < 8192)       { src = wq;    dst = ws + WQ_PK;    g = f; }
  else if (f < 16384) { src = wproj; dst = ws + WPROJ_PK; g = f - 8192; }
  else {
    int j = (f - 16384) >> 14;
    src = j == 0 ? wp1 : j == 1 ? wp2 : j == 2 ? wp3 : wp4;
    dst = ws + WP_PK + (size_t)j * 131072;
    g = (f - 16384) & 16383;
  }
  int l = g & 63, kt = (g >> 6) & 7, nt = g >> 9;
  int n  = nt * 16 + (l & 15);
  int k0 = kt * 32 + (l >> 4) * 8;
  const float* s = src + (size_t)n * 256 + k0;
  u16x8 v;
  #pragma unroll
  for (int j = 0; j < 8; ++j) v[j] = f2bf(s[j]);
  *reinterpret_cast<u16x8*>(dst + (size_t)g * 8) = v;
}

// ---------------------------------------------------------------------------
// K1 (R4-verified): depthwise convs + pointwise (normal MFMA) ->
// kvbuf2[b][row][o] (bf16). 8 batches/block, 512 threads. LDS 86016 B.
// dT [168][256] ushort, swizzled: byte = (row*512 + c*2) ^ ((row&7)<<4)
// ---------------------------------------------------------------------------
__global__ __launch_bounds__(512, 2) void k_kv(
    const float* __restrict__ x,
    const float* __restrict__ wd1, const float* __restrict__ bd1, const float* __restrict__ bp1,
    const float* __restrict__ wd2, const float* __restrict__ bd2, const float* __restrict__ bp2,
    const float* __restrict__ wd3, const float* __restrict__ bd3, const float* __restrict__ bp3,
    const float* __restrict__ wd4, const float* __restrict__ bd4, const float* __restrict__ bp4,
    const uint16_t* __restrict__ ws, uint16_t* __restrict__ kvbuf)
{
  extern __shared__ char smem[];  // 86016 B
  const int t = threadIdx.x, lane = t & 63, w = t >> 6;
  const int b0 = blockIdx.x * 8;

  constexpr int DILA[4] = {1,2,3,4}, PADA[4] = {0,0,1,2}, OWA[4] = {3,2,2,2};
  constexpr int HWA[4]  = {9,4,4,4}, OFFA[4] = {0,9,13,17}, MTA[4] = {5,2,2,2};

  // ---- depthwise conv, all branches; write dT (bf16) to LDS ----
  {
    const int c = t & 255, half = t >> 8;
    for (int pass = 0; pass < 4; ++pass){
      const int bh = pass * 2 + half;
      float xr[49];
      #pragma unroll
      for (int p = 0; p < 49; ++p)
        xr[p] = x[((size_t)(b0 + bh) * 49 + p) * 256 + c];
      #pragma unroll
      for (int j = 0; j < 4; ++j){
        const float* wdp = j==0?wd1:j==1?wd2:j==2?wd3:wd4;
        const float* bdp = j==0?bd1:j==1?bd2:j==2?bd3:bd4;
        float wv[9];
        #pragma unroll
        for (int q = 0; q < 9; ++q) wv[q] = wdp[c * 9 + q];
        const float bdv = bdp[c];
        #pragma unroll
        for (int oy = 0; oy < OWA[j]; ++oy)
        #pragma unroll
        for (int ox = 0; ox < OWA[j]; ++ox){
          float acc = bdv;
          #pragma unroll
          for (int ky = 0; ky < 3; ++ky){
            const int yy = oy * 2 - PADA[j] + ky * DILA[j];
            if (yy < 0 || yy > 6) continue;
            #pragma unroll
            for (int kx = 0; kx < 3; ++kx){
              const int xx = ox * 2 - PADA[j] + kx * DILA[j];
              if (xx < 0 || xx > 6) continue;
              acc += xr[yy * 7 + xx] * wv[ky * 3 + kx];
            }
          }
          const int row = bh * 21 + OFFA[j] + oy * OWA[j] + ox;
          *reinterpret_cast<uint16_t*>(smem + ((row * 512 + c * 2) ^ ((row & 7) << 4))) = f2bf(acc);
        }
      }
    }
  }
  __syncthreads();

  // ---- pointwise GEMM per branch (normal); coalesced 2B stores ----
  #pragma unroll
  for (int j = 0; j < 4; ++j){
    const uint16_t* pk = ws + WP_PK + (size_t)j * 131072;
    const float* bpp = j==0?bp1:j==1?bp2:j==2?bp3:bp4;
    const int hw = HWA[j], off = OFFA[j], MV = hw * 8;
    float bpv[4];
    #pragma unroll
    for (int nt = 0; nt < 4; ++nt) bpv[nt] = bpp[w * 64 + nt * 16 + (lane & 15)];
    for (int mt = 0; mt < MTA[j]; ++mt){
      f32x4 acc[4] = {};
      const int mrow = mt * 16 + (lane & 15);
      const bool av = mrow < MV;
      const int bh = mrow / hw, s = mrow - bh * hw;
      const int arow = bh * 21 + off + s;
      const int abase = arow * 512 + (lane >> 4) * 16;
      #pragma unroll
      for (int kt = 0; kt < 8; ++kt){
        bf16x8 a = {};
        if (av) a = *reinterpret_cast<const bf16x8*>(smem + ((abase + kt * 64) ^ ((arow & 7) << 4)));
        #pragma unroll
        for (int nt = 0; nt < 4; ++nt){
          const int ntg = w * 4 + nt;
          bf16x8 bfr = *reinterpret_cast<const bf16x8*>(pk + (size_t)((ntg * 8 + kt) * 64 + lane) * 8);
          acc[nt] = __builtin_amdgcn_mfma_f32_16x16x32_bf16(a, bfr, acc[nt], 0, 0, 0);
        }
      }
      const int mr2 = mt * 16 + (lane >> 4) * 4;
      #pragma unroll
      for (int i = 0; i < 4; ++i){
        const int m = mr2 + i;
        if (m >= MV) continue;
        const int bh2 = m / hw, s2 = m - bh2 * hw;
        const size_t grow = ((size_t)(b0 + bh2) * 21 + off + s2) * 512;
        #pragma unroll
        for (int nt = 0; nt < 4; ++nt)
          kvbuf[grow + w * 64 + nt * 16 + (lane & 15)] = f2bf(acc[nt][i] + bpv[nt]);
      }
    }
  }
}

// ---------------------------------------------------------------------------
// K2 (R4-verified structure): fused q-proj + attention + out-proj.
// 1 batch/block, 512 threads (8 waves), LDS 64 KB -> 2 blocks/CU.
// Weights (B-frags) read from global (L2-resident).
// R0 [0,32768): x bf16 [64][256] swz; reused per attention pass:
//   KS 4x2KB @0, VT 4x2KB @8192, PA 4x4KB @16384.
// R1 [32768,65536): q/O [token 64][ch 256] bf16 swz.
// kv staging: register-prefetched + v_perm parity deinterleave.
// Only delta vs R4: softmax in exp2 domain (SCALE_Q2 + exp2f, max kept),
// proven in R10.
// ---------------------------------------------------------------------------
__global__ __launch_bounds__(512, 4) void k_attn(
    const float* __restrict__ x, const float* __restrict__ bq,
    const float* __restrict__ bproj, const uint16_t* __restrict__ ws,
    float* __restrict__ out)
{
  extern __shared__ char smem[];   // 65536 B
  constexpr int OSB = 32768;
  const int t = threadIdx.x, lane = t & 63, w = t >> 6;
  const size_t b = blockIdx.x;
  const uint16_t* wq_pk    = ws + WQ_PK;
  const uint16_t* wproj_pk = ws + WPROJ_PK;
  const uint16_t* kvbuf    = ws + KVBUF;

  // ---- kv prefetch state (pass 0), issued before q-proj ----
  const int sh4 = t >> 7, m = (t >> 2) & 31, dch = (t & 3) * 8;
  const bool mv = m < 21;
  uint32_t selK = 0x05040100u, selV = 0x05040100u;
  const uint16_t *rk = kvbuf, *rv = kvbuf;   // safe defaults
  if (mv){
    int off, hw;
    if (m < 9)       { off = 0;  hw = 9; }
    else if (m < 13) { off = 9;  hw = 4; }
    else if (m < 17) { off = 13; hw = 4; }
    else             { off = 17; hw = 4; }
    const int ml = m - off;
    const int c2k = 2 * ml,     ek = c2k >= hw ? 1 : 0, sk = c2k - ek * hw;
    const int c2v = 2 * ml + 1, ev = c2v >= hw ? 1 : 0, sv = c2v - ev * hw;
    selK = ek ? 0x07060302u : 0x05040100u;
    selV = ev ? 0x07060302u : 0x05040100u;
    const int o0 = 2 * (sh4 * 32 + dch);   // pass0 head = sh4
    rk = kvbuf + (b * 21 + off + sk) * 512 + o0;
    rv = kvbuf + (b * 21 + off + sv) * 512 + o0;
  }
  u16x8 L0 = {}, L1 = {}, L2 = {}, L3 = {};
  if (mv){
    L0 = *reinterpret_cast<const u16x8*>(rk);
    L1 = *reinterpret_cast<const u16x8*>(rk + 8);
    L2 = *reinterpret_cast<const u16x8*>(rv);
    L3 = *reinterpret_cast<const u16x8*>(rv + 8);
  }

  // ---- stage x -> bf16 [64][256] swz (rows >=49 zeroed) ----
  {
    const int r = t >> 3, c0 = (t & 7) * 32;
    u16x8 vv[4] = {};
    if (r < 49){
      const float* src = x + (b * 49 + r) * 256 + c0;
      #pragma unroll
      for (int jj = 0; jj < 4; ++jj){
        f32x4 f0 = *reinterpret_cast<const f32x4*>(src + jj * 8);
        f32x4 f1 = *reinterpret_cast<const f32x4*>(src + jj * 8 + 4);
        union { u16x8 v; uint32_t d[4]; } R;
        R.d[0] = cvtpk(f0[0], f0[1]);
        R.d[1] = cvtpk(f0[2], f0[3]);
        R.d[2] = cvtpk(f1[0], f1[1]);
        R.d[3] = cvtpk(f1[2], f1[3]);
        vv[jj] = R.v;
      }
    }
    #pragma unroll
    for (int jj = 0; jj < 4; ++jj)
      *reinterpret_cast<u16x8*>(smem + ((r * 512 + c0 * 2 + jj * 16) ^ ((r & 7) << 4))) = vv[jj];
  }
  __syncthreads();

  // ---- q-proj (no barriers; B-frags from global) ----
  f32x4 qacc[4][2] = {};
  #pragma unroll 2
  for (int kt = 0; kt < 8; ++kt){
    bf16x8 a[4];
    #pragma unroll
    for (int mt = 0; mt < 4; ++mt){
      const int row = mt * 16 + (lane & 15);
      a[mt] = *reinterpret_cast<const bf16x8*>(smem + ((row * 512 + kt * 64 + (lane >> 4) * 16) ^ ((row & 7) << 4)));
    }
    #pragma unroll
    for (int nt = 0; nt < 2; ++nt){
      bf16x8 bfr = *reinterpret_cast<const bf16x8*>(wq_pk + (size_t)(((w * 2 + nt) * 8 + kt) * 64 + lane) * 8);
      #pragma unroll
      for (int mt = 0; mt < 4; ++mt)
        qacc[mt][nt] = __builtin_amdgcn_mfma_f32_16x16x32_bf16(a[mt], bfr, qacc[mt][nt], 0, 0, 0);
    }
  }
  // q (bias+scale, bf16) -> R1  (SCALE_Q2: exp2-domain softmax)
  #pragma unroll
  for (int nt = 0; nt < 2; ++nt){
    const int col = w * 32 + nt * 16 + (lane & 15);
    const float bqv = bq[col];
    #pragma unroll
    for (int mt = 0; mt < 4; ++mt)
      #pragma unroll
      for (int i = 0; i < 4; ++i){
        const int row = mt * 16 + (lane >> 4) * 4 + i;
        *reinterpret_cast<uint16_t*>(smem + OSB + ((row * 512 + col * 2) ^ ((row & 7) << 4)))
          = f2bf((qacc[mt][nt][i] + bqv) * SCALE_Q2);
      }
  }
  __syncthreads();   // x consumed; q visible; R0 free for KS/VT/PA

  // ---- attention: 2 passes x 4 heads, 2 waves/head ----
  for (int p = 0; p < 2; ++p){
    { // extract prefetched kv -> KS (vector) / VT (transposed scatter)
      u16x8 kf = extract_par(L0, L1, selK);
      u16x8 vf = extract_par(L2, L3, selV);
      *reinterpret_cast<u16x8*>(smem + sh4 * 2048 + ((m * 64 + dch * 2) ^ ((m & 7) << 4))) = kf;
      #pragma unroll
      for (int jj = 0; jj < 8; ++jj){
        const int d = dch + jj;
        *reinterpret_cast<uint16_t*>(smem + 8192 + sh4 * 2048 + ((d * 64 + m * 2) ^ ((d & 7) << 4))) = vf[jj];
      }
      if (p == 0 && mv){  // prefetch pass-1 (head = 4+sh4 -> +256 elems)
        L0 = *reinterpret_cast<const u16x8*>(rk + 256);
        L1 = *reinterpret_cast<const u16x8*>(rk + 264);
        L2 = *reinterpret_cast<const u16x8*>(rv + 256);
        L3 = *reinterpret_cast<const u16x8*>(rv + 264);
      }
    }
    __syncthreads();

    const int h4 = w >> 1, wh = w & 1;
    const int hcol = (p * 4 + h4) * 64;   // byte col offset of this head in R1
    const int pabase = 16384 + h4 * 4096;

    // scores: M=32 rows (2 mt), N=32 kv slots (2 nt), K=32 dims
    bf16x8 bk[2];
    #pragma unroll
    for (int nt = 0; nt < 2; ++nt){
      const int m0 = nt * 16 + (lane & 15);
      bk[nt] = *reinterpret_cast<const bf16x8*>(smem + h4 * 2048 + ((m0 * 64 + (lane >> 4) * 16) ^ ((m0 & 7) << 4)));
    }
    f32x4 sacc[2][2];
    #pragma unroll
    for (int mt = 0; mt < 2; ++mt){
      const int row = wh * 32 + mt * 16 + (lane & 15);
      bf16x8 aq = *reinterpret_cast<const bf16x8*>(smem + OSB + ((row * 512 + hcol + (lane >> 4) * 16) ^ ((row & 7) << 4)));
      #pragma unroll
      for (int nt = 0; nt < 2; ++nt){
        f32x4 z = {};
        sacc[mt][nt] = __builtin_amdgcn_mfma_f32_16x16x32_bf16(aq, bk[nt], z, 0, 0, 0);
      }
    }
    // softmax (21 valid slots) in C-frag layout, exp2 domain; P -> PA
    const bool ok1 = (lane & 15) < 5;
    #pragma unroll
    for (int mt = 0; mt < 2; ++mt)
      #pragma unroll
      for (int i = 0; i < 4; ++i){
        const float s0 = sacc[mt][0][i];
        const float s1 = sacc[mt][1][i];
        float mx = fmaxf(s0, ok1 ? s1 : -3.0e38f);
        #pragma unroll
        for (int dd = 1; dd < 16; dd <<= 1) mx = fmaxf(mx, __shfl_xor(mx, dd));
        const float e0 = exp2f(s0 - mx);
        const float e1 = ok1 ? exp2f(s1 - mx) : 0.f;
        float sm = e0 + e1;
        #pragma unroll
        for (int dd = 1; dd < 16; dd <<= 1) sm += __shfl_xor(sm, dd);
        const float inv = 1.0f / sm;
        const int pr = wh * 32 + mt * 16 + (lane >> 4) * 4 + i;
        const int c0 = lane & 15;
        *reinterpret_cast<uint16_t*>(smem + pabase + ((pr * 64 + c0 * 2) ^ ((pr & 7) << 4))) = f2bf(e0 * inv);
        *reinterpret_cast<uint16_t*>(smem + pabase + ((pr * 64 + (c0 + 16) * 2) ^ ((pr & 7) << 4))) = f2bf(e1 * inv);
      }
    // PV (produce/consume within wave): M=32 rows, N=32 dims, K=32 slots
    f32x4 oacc[2][2];
    #pragma unroll
    for (int mt = 0; mt < 2; ++mt){
      const int pr = wh * 32 + mt * 16 + (lane & 15);
      bf16x8 ap = *reinterpret_cast<const bf16x8*>(smem + pabase + ((pr * 64 + (lane >> 4) * 16) ^ ((pr & 7) << 4)));
      #pragma unroll
      for (int nt = 0; nt < 2; ++nt){
        const int d0 = nt * 16 + (lane & 15);
        bf16x8 bv = *reinterpret_cast<const bf16x8*>(smem + 8192 + h4 * 2048 + ((d0 * 64 + (lane >> 4) * 16) ^ ((d0 & 7) << 4)));
        f32x4 z = {};
        oacc[mt][nt] = __builtin_amdgcn_mfma_f32_16x16x32_bf16(ap, bv, z, 0, 0, 0);
      }
    }
    // O -> R1 (own head cols)
    #pragma unroll
    for (int mt = 0; mt < 2; ++mt)
      #pragma unroll
      for (int nt = 0; nt < 2; ++nt)
        #pragma unroll
        for (int i = 0; i < 4; ++i){
          const int row = wh * 32 + mt * 16 + (lane >> 4) * 4 + i;
          const int colb = hcol + (nt * 16 + (lane & 15)) * 2;
          *reinterpret_cast<uint16_t*>(smem + OSB + ((row * 512 + colb) ^ ((row & 7) << 4))) = f2bf(oacc[mt][nt][i]);
        }
    __syncthreads();
  }

  // ---- out-proj (no barriers; B-frags from global) ----
  f32x4 pacc[4][2] = {};
  #pragma unroll 2
  for (int kt = 0; kt < 8; ++kt){
    bf16x8 a[4];
    #pragma unroll
    for (int mt = 0; mt < 4; ++mt){
      const int row = mt * 16 + (lane & 15);
      a[mt] = *reinterpret_cast<const bf16x8*>(smem + OSB + ((row * 512 + kt * 64 + (lane >> 4) * 16) ^ ((row & 7) << 4)));
    }
    #pragma unroll
    for (int nt = 0; nt < 2; ++nt){
      bf16x8 bfr = *reinterpret_cast<const bf16x8*>(wproj_pk + (size_t)(((w * 2 + nt) * 8 + kt) * 64 + lane) * 8);
      #pragma unroll
      for (int mt = 0; mt < 4; ++mt)
        pacc[mt][nt] = __builtin_amdgcn_mfma_f32_16x16x32_bf16(a[mt], bfr, pacc[mt][nt], 0, 0, 0);
    }
  }
  #pragma unroll
  for (int nt = 0; nt < 2; ++nt){
    const int col = w * 32 + nt * 16 + (lane & 15);
    const float bpv = bproj[col];
    #pragma unroll
    for (int mt = 0; mt < 4; ++mt)
      #pragma unroll
      for (int i = 0; i < 4; ++i){
        const int n = mt * 16 + (lane >> 4) * 4 + i;
        if (n < 49)
          out[(b * 49 + n) * 256 + col] = pacc[mt][nt][i] + bpv;
      }
  }
}

// ---------------------------------------------------------------------------
extern "C" void kernel_launch(void* const* d_in, const int* in_sizes, int n_in,
                              void* d_out, int out_size, void* d_ws, size_t ws_size,
                              hipStream_t stream)
{
  const float* x     = (const float*)d_in[0];
  const float* wq    = (const float*)d_in[1];
  const float* bq    = (const float*)d_in[2];
  const float* wd1   = (const float*)d_in[3];
  const float* bd1   = (const float*)d_in[4];
  const float* wp1   = (const float*)d_in[5];
  const float* bp1   = (const float*)d_in[6];
  const float* wd2   = (const float*)d_in[7];
  const float* bd2   = (const float*)d_in[8];
  const float* wp2   = (const float*)d_in[9];
  const float* bp2   = (const float*)d_in[10];
  const float* wd3   = (const float*)d_in[11];
  const float* bd3   = (const float*)d_in[12];
  const float* wp3   = (const float*)d_in[13];
  const float* bp3   = (const float*)d_in[14];
  const float* wd4   = (const float*)d_in[15];
  const float* bd4   = (const float*)d_in[16];
  const float* wp4   = (const float*)d_in[17];
  const float* bp4   = (const float*)d_in[18];
  const float* wproj = (const float*)d_in[19];
  const float* bproj = (const float*)d_in[20];
  uint16_t* ws = (uint16_t*)d_ws;
  float* out = (float*)d_out;

  k_prepack<<<320, 256, 0, stream>>>(wq, wp1, wp2, wp3, wp4, wproj, ws);
  k_kv<<<512, 512, 86016, stream>>>(x, wd1, bd1, bp1, wd2, bd2, bp2,
                                    wd3, bd3, bp3, wd4, bd4, bp4,
                                    ws, ws + KVBUF);
  k_attn<<<4096, 512, 65536, stream>>>(x, bq, bproj, ws, out);
}